// Round 2
// baseline (400.637 us; speedup 1.0000x reference)
//
#include <hip/hip_runtime.h>
#include <stdint.h>

// ---------------------------------------------------------------------------
// Reference semantics (bit-level):
//   row = 64 floats, each exactly 0.0 or 1.0, encoding an FP64 bit pattern:
//     pos 0      : sign
//     pos 1..11  : exponent, MSB first
//     pos 12..63 : mantissa
//   e      = int(bits 1..11, MSB first)
//   e_real = (e + 1025) & 0x7FF          // add -1023 (11-bit 2's compl, carry dropped)
//   is_odd = e_real & 1
//   e_half = (e_real >> 1) | (e_real & 0x400)   // shift right, duplicate sign bit
//   e_new  = (e_half + 1023) & 0x7FF
//   out    = [0, bits of e_new MSB first, is_odd ? sqrt2_mant_bits : 0]
// ---------------------------------------------------------------------------

typedef float vf4 __attribute__((ext_vector_type(4)));  // nontemporal-builtin-friendly

constexpr uint64_t SQRT2_MANT = 1865452045155277ULL;  // 52-bit mantissa of sqrt(2)

constexpr uint64_t rev64c(uint64_t x) {
    uint64_t r = 0;
    for (int i = 0; i < 64; ++i) r |= ((x >> i) & 1ULL) << (63 - i);
    return r;
}
// SQRT2_REV bit p == SQRT2_MANT bit (63-p); bits 0..11 are zero.
constexpr uint64_t SQRT2_REV = rev64c(SQRT2_MANT);

// One lane per float4 output chunk. 16 chunks per row; lanes [g..g+15] of each
// 16-lane group share one row. Lanes with (chunk&15)<3 load the first 48B of
// the row (covers input positions 0..11); ds_swizzle broadcasts the three
// packed nibbles to the whole group.
__global__ __launch_bounds__(256) void SpikeFP64Sqrt_kernel(
    const vf4* __restrict__ in4, vf4* __restrict__ out4, int n4) {
    const int tid    = blockIdx.x * blockDim.x + threadIdx.x;
    const int stride = gridDim.x * blockDim.x;   // multiple of 16

    for (int c = tid; c < n4; c += stride) {
        const int sub = c & 15;                  // chunk index within the row

        vf4 f = (vf4)(0.f);
        if (sub < 3) f = in4[c];                 // exec-masked 16B load, first sector only

        // pack this chunk's 4 bits (values are exactly 0.0 or 1.0)
        unsigned nib = (unsigned)f.x | ((unsigned)f.y << 1) |
                       ((unsigned)f.z << 2) | ((unsigned)f.w << 3);

        // broadcast nibbles of lanes k=0,1,2 within each 16-lane group.
        // BitMode pattern: src = (lane & 0x10) | k  ->  imm = (k<<5) | 0x10
        unsigned n0 = (unsigned)__builtin_amdgcn_ds_swizzle((int)nib, 0x0010);
        unsigned n1 = (unsigned)__builtin_amdgcn_ds_swizzle((int)nib, 0x0030);
        unsigned n2 = (unsigned)__builtin_amdgcn_ds_swizzle((int)nib, 0x0050);

        // w bit p = input bit at row position p, p = 0..11
        unsigned w = n0 | (n1 << 4) | (n2 << 8);

        // e = sum_{p=1..11} x_p << (11-p)  (MSB-first exponent), drop sign bit
        unsigned e      = (__brev(w) >> 20) & 0x7FFu;
        unsigned e_real = (e + 1025u) & 0x7FFu;
        unsigned is_odd = e_real & 1u;
        unsigned e_half = (e_real >> 1) | (e_real & 0x400u);
        unsigned e_new  = (e_half + 1023u) & 0x7FFu;

        // outw bit p = output value at row position p
        //   bits 1..11: e_new MSB-first ; bits 12..63: is_odd ? sqrt2 bits : 0
        uint64_t A    = (uint64_t)(__brev(e_new) >> 21);       // A bit q = e_new bit (10-q)
        uint64_t outw = (A << 1) | (SQRT2_REV & (0ULL - (uint64_t)is_odd));

        unsigned bits = (unsigned)(outw >> (sub << 2)) & 0xFu;

        vf4 o;
        o.x = (float)(bits & 1u);
        o.y = (float)((bits >> 1) & 1u);
        o.z = (float)((bits >> 2) & 1u);
        o.w = (float)((bits >> 3) & 1u);
        __builtin_nontemporal_store(o, &out4[c]);  // coalesced 256B/wave store
    }
}

extern "C" void kernel_launch(void* const* d_in, const int* in_sizes, int n_in,
                              void* d_out, int out_size, void* d_ws, size_t ws_size,
                              hipStream_t stream) {
    const vf4* in4  = (const vf4*)d_in[0];
    vf4*       out4 = (vf4*)d_out;
    const int n4 = out_size / 4;          // 16,777,216 float4 chunks

    const int block = 256;
    const int grid  = 2048;               // 8 blocks/CU on 256 CUs, grid-stride x32
    SpikeFP64Sqrt_kernel<<<grid, block, 0, stream>>>(in4, out4, n4);
}

// Round 3
// 399.245 us; speedup vs baseline: 1.0035x; 1.0035x over previous
//
#include <hip/hip_runtime.h>
#include <stdint.h>

// ---------------------------------------------------------------------------
// Bit-level semantics of the reference (row = 64 floats, each exactly 0/1,
// encoding an FP64 bit pattern MSB-first):
//   e      = int(bits 1..11)
//   e_real = (e + 1025) & 0x7FF            // ripple add of -1023, carry dropped
//   is_odd = e_real & 1
//   e_half = (e_real >> 1) | (e_real & 0x400)
//   e_new  = (e_half + 1023) & 0x7FF
//   out    = [0, e_new bits MSB-first, is_odd ? sqrt2_mant bits : 0]
// ---------------------------------------------------------------------------

typedef float vf4 __attribute__((ext_vector_type(4)));

constexpr uint64_t SQRT2_MANT = 1865452045155277ULL;  // 52-bit mantissa of sqrt(2)

constexpr uint64_t rev64c(uint64_t x) {
    uint64_t r = 0;
    for (int i = 0; i < 64; ++i) r |= ((x >> i) & 1ULL) << (63 - i);
    return r;
}
// SQRT2_REV bit p == SQRT2_MANT bit (63-p); bits 0..11 are zero.
constexpr uint64_t SQRT2_REV = rev64c(SQRT2_MANT);

// One lane per float4 output chunk; 16 lanes (one group) share a row.
// Lane with sub<12 loads dword `sub` of its row (48B = 1 sector per row);
// one __ballot assembles the 4 rows' bit vectors for the whole wave.
__global__ __launch_bounds__(256) void SpikeFP64Sqrt_kernel(
    const float* __restrict__ in, vf4* __restrict__ out4, int n4) {
    const int tid    = blockIdx.x * blockDim.x + threadIdx.x;
    const int stride = gridDim.x * blockDim.x;   // multiple of 64
    const int g      = (threadIdx.x & 63) >> 4;  // 16-lane group within wave

    #pragma unroll 4
    for (int c = tid; c < n4; c += stride) {
        const int sub = c & 15;                  // chunk index within the row

        float x = 0.f;
        if (sub < 12) x = in[(size_t)(c >> 4) * 64 + sub];  // 1 dword/lane, 12 lanes/group

        // ballot bit l = (row bit) for lane l; group g's row occupies bits [16g,16g+15]
        const uint64_t m = __ballot(x != 0.0f);
        const unsigned w = ((unsigned)(m >> (g << 4))) & 0xFFEu;  // bits 1..11 (skip sign)

        // e = bits 1..11 MSB-first
        unsigned e      = (__brev(w) >> 20) & 0x7FFu;
        unsigned e_real = (e + 1025u) & 0x7FFu;
        unsigned is_odd = e_real & 1u;
        unsigned e_half = (e_real >> 1) | (e_real & 0x400u);
        unsigned e_new  = (e_half + 1023u) & 0x7FFu;

        // outw bit p = output value at row position p
        uint64_t A    = (uint64_t)(__brev(e_new) >> 21);  // A bit q = e_new bit (10-q)
        uint64_t outw = (A << 1) | (SQRT2_REV & (0ULL - (uint64_t)is_odd));

        unsigned bits = (unsigned)(outw >> (sub << 2)) & 0xFu;

        vf4 o;
        o.x = (float)(bits & 1u);
        o.y = (float)((bits >> 1) & 1u);
        o.z = (float)((bits >> 2) & 1u);
        o.w = (float)((bits >> 3) & 1u);
        out4[c] = o;                              // plain coalesced 256B/wave store
    }
}

extern "C" void kernel_launch(void* const* d_in, const int* in_sizes, int n_in,
                              void* d_out, int out_size, void* d_ws, size_t ws_size,
                              hipStream_t stream) {
    const float* in   = (const float*)d_in[0];
    vf4*         out4 = (vf4*)d_out;
    const int n4 = out_size / 4;          // 16,777,216 float4 chunks

    const int block = 256;
    const int grid  = 2048;               // 8 blocks/CU on 256 CUs, grid-stride x32
    SpikeFP64Sqrt_kernel<<<grid, block, 0, stream>>>(in, out4, n4);
}